// Round 10
// baseline (766.723 us; speedup 1.0000x reference)
//
#include <hip/hip_runtime.h>
#include <hip/hip_bf16.h>
#include <math.h>

#define B_ 8
#define N_ 2048
#define KNN 20
#define CH 64

typedef unsigned int u32;
typedef unsigned short ushort16;
typedef __attribute__((ext_vector_type(8))) short s8v;   // 8 bf16 = 4 VGPR (MFMA A/B frag)
typedef __attribute__((ext_vector_type(4))) float f4v;   // MFMA C/D frag

__device__ __forceinline__ float lrelu(float z) { return z >= 0.0f ? z : 0.2f * z; }

__device__ __forceinline__ u32 enc_f32(float f) {
  u32 u = __float_as_uint(f);
  return (u & 0x80000000u) ? ~u : (u | 0x80000000u);
}
__device__ __forceinline__ float dec_f32(u32 u) {
  u32 bits = (u & 0x80000000u) ? (u ^ 0x80000000u) : ~u;
  return __uint_as_float(bits);
}
__device__ __forceinline__ ushort16 f2bf(float f) {   // RNE bf16
  u32 u = __float_as_uint(f);
  u = (u + 0x7fffu + ((u >> 16) & 1u)) >> 16;
  return (ushort16)u;
}
__device__ __forceinline__ float bf2f(ushort16 h) { return __uint_as_float(((u32)h) << 16); }

__device__ __forceinline__ float rdlane(float v, int lane) {
  return __int_as_float(__builtin_amdgcn_readlane(__float_as_int(v), lane));
}

// 3-way split of 8 contiguous fp32: v = a0 + a1 + a2 (covers all 24 mantissa bits)
__device__ __forceinline__ void split3(const float* __restrict__ p, s8v& a0, s8v& a1, s8v& a2) {
#pragma unroll
  for (int j = 0; j < 8; ++j) {
    float v = p[j];
    ushort16 h0 = f2bf(v);
    float r = v - bf2f(h0);                 // exact
    u32 ru = __float_as_uint(r);
    a0[j] = (short)h0;
    a1[j] = (short)(ru >> 16);              // truncation
    float r2 = r - __uint_as_float(ru & 0xFFFF0000u);  // exact
    a2[j] = (short)f2bf(r2);
  }
}

// 6-product fp32-grade MFMA: acc += (A0+A1+A2)(B0+B1+B2) minus O(2^-25) terms
#define MFMA6(ACC, A0, A1, A2, B0, B1, B2)                                   \
  ACC = __builtin_amdgcn_mfma_f32_16x16x32_bf16(A0, B0, ACC, 0, 0, 0);       \
  ACC = __builtin_amdgcn_mfma_f32_16x16x32_bf16(A0, B1, ACC, 0, 0, 0);       \
  ACC = __builtin_amdgcn_mfma_f32_16x16x32_bf16(A1, B0, ACC, 0, 0, 0);       \
  ACC = __builtin_amdgcn_mfma_f32_16x16x32_bf16(A0, B2, ACC, 0, 0, 0);       \
  ACC = __builtin_amdgcn_mfma_f32_16x16x32_bf16(A1, B1, ACC, 0, 0, 0);       \
  ACC = __builtin_amdgcn_mfma_f32_16x16x32_bf16(A2, B0, ACC, 0, 0, 0);

__device__ __forceinline__ void wsplit(float v, ushort16& h0, ushort16& h1, ushort16& h2) {
  h0 = f2bf(v);
  float r = v - bf2f(h0);
  h1 = f2bf(r);
  float r2 = r - bf2f(h1);
  h2 = f2bf(r2);
}

// ---------------- prep: float4 weight quads (bit-exact copies) + MFMA6 packs + gkeys ----------------
// B-frag lane map (16x16x32): col = l&15, k = (l>>4)*8 + j.
__global__ __launch_bounds__(256) void prep_kernel(
    const float* __restrict__ W2, const float* __restrict__ W3, const float* __restrict__ W4,
    const float* __restrict__ W5, const float* __restrict__ W6,
    float4* __restrict__ w2p, float4* __restrict__ w3p, float4* __restrict__ w4p,
    ushort16* __restrict__ wp5h, ushort16* __restrict__ wp5m, ushort16* __restrict__ wp5l,
    ushort16* __restrict__ wp6h, ushort16* __restrict__ wp6m, ushort16* __restrict__ wp6l,
    u32* __restrict__ gkeys) {
  int i = blockIdx.x * 256 + threadIdx.x;
  if (i < 196608) {              // wp6 pack: t = kk*64+nt (kk<6), d = kk*32+(l>>4)*8+j, ch = nt*16+(l&15)
    int j = i & 7, l = (i >> 3) & 63, t = i >> 9;
    int kk = t >> 6, nt = t & 63;
    int d = kk * 32 + ((l >> 4) << 3) + j;
    int ch = nt * 16 + (l & 15);
    ushort16 a, b, c;
    wsplit(W6[ch * 192 + d], a, b, c);
    wp6h[i] = a; wp6m[i] = b; wp6l[i] = c;
  }
  if (i < 8192) {
    gkeys[i] = 0u;
    // MFMA6 pack for W5 (Wcat: d<64 -> WA; d>=64 -> WB-WA)
    int j = i & 7, l = (i >> 3) & 63, tile = i >> 9;
    int kk = tile >> 2, nt = tile & 3;
    int d = kk * 32 + ((l >> 4) << 3) + j;
    int ch = nt * 16 + (l & 15);
    float v5 = (d < 64) ? W5[ch * 128 + d] : (W5[ch * 128 + d] - W5[ch * 128 + d - 64]);
    ushort16 a, b, c;
    wsplit(v5, a, b, c); wp5h[i] = a; wp5m[i] = b; wp5l[i] = c;
  }
  if (i < 2048) {                // w3p[g*64+c] = W3[c][4g..4g+3], g<32 (a-quads g<16, q-quads g>=16)
    int g = i >> 6, c_ = i & 63;
    w3p[i] = *(const float4*)&W3[c_ * 128 + 4 * g];
  }
  if (i < 1024) {                // w2p/w4p[g*64+c] = W[c][4g..4g+3]
    int g = i >> 6, c_ = i & 63;
    w2p[i] = *(const float4*)&W2[c_ * 64 + 4 * g];
    w4p[i] = *(const float4*)&W4[c_ * 64 + 4 * g];
  }
}

// ---------------- KNN: fp32 filter + fp64 rerank (R3 verbatim) ----------------
#define QPB 32
#define SL 8
#define CSL (N_ / SL)
#define CAP 31

__global__ __launch_bounds__(256) void knn_kernel(const float* __restrict__ p, int ld, int off,
                                                  int* __restrict__ idxout) {
  __shared__ __align__(16) char arena[64640];
  float4* pts = (float4*)arena;
  int* buf = (int*)(arena + 32896);
  double* dls = (double*)arena;
  int* ils = (int*)(arena + 40960);

  const int b = blockIdx.y;
  const float* pb = p + (size_t)b * N_ * ld + off;
  for (int j = threadIdx.x; j < N_; j += 256) {
    pts[j + (j >> 8)] = make_float4(pb[(size_t)j * ld + 0], pb[(size_t)j * ld + 1],
                                    pb[(size_t)j * ld + 2], 0.f);
  }
  __syncthreads();

  const int t = threadIdx.x & 7;
  const int qloc = threadIdx.x >> 3;
  const int q = blockIdx.x * QPB + qloc;
  const float4 qp = pts[q + (q >> 8)];
  const int jb = t * CSL;
  const float4* myp = pts + jb + t;

  float d0 = 1e30f, d1 = 1e30f, d2 = 1e30f;
#pragma unroll 4
  for (int i = 0; i < CSL; ++i) {
    float4 c = myp[i];
    float dx = qp.x - c.x, dy = qp.y - c.y, dz = qp.z - c.z;
    float d = fmaf(dz, dz, fmaf(dy, dy, dx * dx));
    float lo = fminf(d, d0); float hi = fmaxf(d, d0); d0 = lo;
    float m1 = fminf(d1, hi); float c1 = fmaxf(d1, hi); d1 = m1;
    d2 = fminf(d2, c1);
  }
  float thr = d2;
#pragma unroll
  for (int s = 1; s < 8; s <<= 1) thr = fmaxf(thr, __shfl_xor(thr, s));
  thr = thr * 1.0001f + 1e-7f;

  int cnt = 0;
  int* mybuf = buf + threadIdx.x * CAP;
#pragma unroll 4
  for (int i = 0; i < CSL; ++i) {
    float4 c = myp[i];
    float dx = qp.x - c.x, dy = qp.y - c.y, dz = qp.z - c.z;
    float d = fmaf(dz, dz, fmaf(dy, dy, dx * dx));
    if (d <= thr) {
      if (cnt < CAP) mybuf[cnt] = jb + i;
      ++cnt;
    }
  }

  double ld_[KNN]; int li_[KNN];
#pragma unroll
  for (int u = 0; u < KNN; ++u) { ld_[u] = 1e300; li_[u] = 0x7fffffff; }

  const bool ovf = cnt > CAP;
  const int m = ovf ? 0 : cnt;
  for (int e = 0; e < m; ++e) {
    int j = mybuf[e];
    float4 c = pts[j + (j >> 8)];
    double dx = (double)qp.x - (double)c.x;
    double dy = (double)qp.y - (double)c.y;
    double dz = (double)qp.z - (double)c.z;
    double d = dx * dx + dy * dy + dz * dz;
    if (d < ld_[KNN - 1]) {
      ld_[KNN - 1] = d; li_[KNN - 1] = j;
#pragma unroll
      for (int u = KNN - 1; u > 0; --u) {
        if (ld_[u] < ld_[u - 1]) {
          double td = ld_[u]; ld_[u] = ld_[u - 1]; ld_[u - 1] = td;
          int ti = li_[u]; li_[u] = li_[u - 1]; li_[u - 1] = ti;
        }
      }
    }
  }
  if (ovf) {
    for (int i = 0; i < CSL; ++i) {
      int j = jb + i;
      float4 c = myp[i];
      double dx = (double)qp.x - (double)c.x;
      double dy = (double)qp.y - (double)c.y;
      double dz = (double)qp.z - (double)c.z;
      double d = dx * dx + dy * dy + dz * dz;
      if (d < ld_[KNN - 1]) {
        ld_[KNN - 1] = d; li_[KNN - 1] = j;
#pragma unroll
        for (int u = KNN - 1; u > 0; --u) {
          if (ld_[u] < ld_[u - 1]) {
            double td = ld_[u]; ld_[u] = ld_[u - 1]; ld_[u - 1] = td;
            int ti = li_[u]; li_[u] = li_[u - 1]; li_[u - 1] = ti;
          }
        }
      }
    }
  }
  __syncthreads();
#pragma unroll
  for (int u = 0; u < KNN; ++u) {
    dls[threadIdx.x * KNN + u] = ld_[u];
    ils[threadIdx.x * KNN + u] = li_[u];
  }
  __syncthreads();

  if (t == 0) {
    int h0 = 0, h1 = 0, h2 = 0, h3 = 0, h4 = 0, h5 = 0, h6 = 0, h7 = 0;
    const int lb = qloc * 8;
    int* outp = idxout + ((size_t)b * N_ + q) * KNN;
    for (int r = 0; r < KNN; ++r) {
      double bd = 1e301; int bi = 0x7fffffff; int bt = 0;
#define CONSIDER(T, H)                                                     \
      { int li2 = (lb + (T)) * KNN + (H);                                  \
        double dv = dls[li2]; int iv = ils[li2];                           \
        if (dv < bd || (dv == bd && iv < bi)) { bd = dv; bi = iv; bt = (T); } }
      CONSIDER(0, h0) CONSIDER(1, h1) CONSIDER(2, h2) CONSIDER(3, h3)
      CONSIDER(4, h4) CONSIDER(5, h5) CONSIDER(6, h6) CONSIDER(7, h7)
#undef CONSIDER
      outp[r] = bi;
      h0 += (bt == 0); h1 += (bt == 1); h2 += (bt == 2); h3 += (bt == 3);
      h4 += (bt == 4); h5 += (bt == 5); h6 += (bt == 6); h7 += (bt == 7);
    }
  }
}

// ---------------- stage1: bit-exact fp32 (x1b feeds KNN); GEMM2 hybrid LDS/readlane ----------------
__global__ __launch_bounds__(256) void stage1_kernel(
    const float* __restrict__ x, const int* __restrict__ idx,
    const float* __restrict__ W1, const float4* __restrict__ w2p,
    const float* __restrict__ g0, const float* __restrict__ b0,
    const float* __restrict__ m0, const float* __restrict__ v0,
    const float* __restrict__ g1, const float* __restrict__ b1,
    const float* __restrict__ m1, const float* __restrict__ v1,
    float* __restrict__ x1out) {
  __shared__ float nbs[4][KNN][3];
  __shared__ float ctrs[4][3];
  __shared__ int sidx[4][KNN];
  __shared__ float h1s[4][KNN * CH];   // 20KB wave-local h1 staging
  const int b = blockIdx.y;
  const int n0 = blockIdx.x * 4;
  const int p = threadIdx.x >> 6, c = threadIdx.x & 63;

  for (int i = threadIdx.x; i < 4 * KNN; i += 256)
    sidx[i / KNN][i % KNN] = idx[((size_t)b * N_ + n0 + i / KNN) * KNN + i % KNN];
  __syncthreads();
  for (int i = threadIdx.x; i < 4 * KNN * 3; i += 256) {
    int pp = i / (KNN * 3), r = i % (KNN * 3), k = r / 3, d = r % 3;
    nbs[pp][k][d] = x[((size_t)b * N_ + sidx[pp][k]) * 3 + d];
  }
  if (threadIdx.x < 12) {
    int pp = threadIdx.x / 3, d = threadIdx.x % 3;
    ctrs[pp][d] = x[((size_t)b * N_ + n0 + pp) * 3 + d];
  }
  __syncthreads();

  float sc0, sh0, sc1, sh1;
  {
    double rs = 1.0 / sqrt((double)v0[c] + 1e-5);
    sc0 = (float)((double)g0[c] * rs); sh0 = b0[c] - m0[c] * sc0;
    rs = 1.0 / sqrt((double)v1[c] + 1e-5);
    sc1 = (float)((double)g1[c] * rs); sh1 = b1[c] - m1[c] * sc1;
  }

  const float cx = ctrs[p][0], cy = ctrs[p][1], cz = ctrs[p][2];
  const float wa0 = W1[c * 6 + 0], wa1 = W1[c * 6 + 1], wa2 = W1[c * 6 + 2];
  const float wb0 = W1[c * 6 + 3], wb1 = W1[c * 6 + 4], wb2 = W1[c * 6 + 5];
  const float cbase = cx * wb0 + cy * wb1 + cz * wb2;

  float h1r[KNN];
#pragma unroll
  for (int k = 0; k < KNN; ++k) {
    float a = (nbs[p][k][0] - cx) * wa0 + (nbs[p][k][1] - cy) * wa1 + (nbs[p][k][2] - cz) * wa2 + cbase;
    h1r[k] = lrelu(a * sc0 + sh0);
  }

  // stage h1 in wave-local LDS (same bits); even g read from LDS, odd g via readlane
  float* hp = h1s[p];
#pragma unroll
  for (int k = 0; k < KNN; ++k) hp[k * CH + c] = h1r[k];

  float acc2[KNN];
#pragma unroll
  for (int k = 0; k < KNN; ++k) acc2[k] = 0.f;
#pragma unroll 2
  for (int g = 0; g < 16; ++g) {       // cc = 4g..4g+3, ascending (same FMA order as scalar cc loop)
    const float4 w = w2p[g * 64 + c];
    if (g & 1) {
#pragma unroll
      for (int k = 0; k < KNN; ++k) {
        float hx = rdlane(h1r[k], g * 4 + 0);
        float hy = rdlane(h1r[k], g * 4 + 1);
        float hz = rdlane(h1r[k], g * 4 + 2);
        float hw = rdlane(h1r[k], g * 4 + 3);
        acc2[k] += hx * w.x; acc2[k] += hy * w.y; acc2[k] += hz * w.z; acc2[k] += hw * w.w;
      }
    } else {
#pragma unroll
      for (int k = 0; k < KNN; ++k) {
        const float4 hv = *(const float4*)&hp[k * CH + g * 4];
        acc2[k] += hv.x * w.x; acc2[k] += hv.y * w.y; acc2[k] += hv.z * w.z; acc2[k] += hv.w * w.w;
      }
    }
  }
  float mx = -INFINITY;
#pragma unroll
  for (int k = 0; k < KNN; ++k) mx = fmaxf(mx, lrelu(acc2[k] * sc1 + sh1));
  x1out[((size_t)b * N_ + n0 + p) * CH + c] = mx;
}

// ---------------- stage2: bit-exact fp32 (x2b feeds KNN) ----------------
// GEMM1 operands (nbs/ctrs rows) read directly from global via wave-uniform addresses
// (off the LDS pipe: s_load/L1); GEMM2 hybrid even-g LDS / odd-g readlane.
__global__ __launch_bounds__(256) void stage2_kernel(
    const float* __restrict__ xin, const int* __restrict__ idx,
    const float4* __restrict__ w3p, const float4* __restrict__ w4p,
    const float* __restrict__ g0, const float* __restrict__ b0,
    const float* __restrict__ m0, const float* __restrict__ v0,
    const float* __restrict__ g1, const float* __restrict__ b1,
    const float* __restrict__ m1, const float* __restrict__ v1,
    float* __restrict__ xout) {
  __shared__ int sidx[4][KNN];
  __shared__ float h1s[4][KNN * CH];   // 20KB per-wave h1 staging
  const int b = blockIdx.y, n0 = blockIdx.x * 4;
  const int p = threadIdx.x >> 6, c = threadIdx.x & 63;

  for (int i = threadIdx.x; i < 4 * KNN; i += 256)
    sidx[i / KNN][i % KNN] = idx[((size_t)b * N_ + n0 + i / KNN) * KNN + i % KNN];
  __syncthreads();

  // wave-uniform neighbor rows -> scalar regs (readfirstlane makes uniformity provable)
  int nrow[KNN];
#pragma unroll
  for (int k = 0; k < KNN; ++k) nrow[k] = __builtin_amdgcn_readfirstlane(sidx[p][k]);
  const float* xct = xin + ((size_t)b * N_ + n0 + p) * CH;

  float sc0, sh0, sc1, sh1;
  {
    double rs = 1.0 / sqrt((double)v0[c] + 1e-5);
    sc0 = (float)((double)g0[c] * rs); sh0 = b0[c] - m0[c] * sc0;
    rs = 1.0 / sqrt((double)v1[c] + 1e-5);
    sc1 = (float)((double)g1[c] * rs); sh1 = b1[c] - m1[c] * sc1;
  }

  float acc[KNN];
#pragma unroll
  for (int k = 0; k < KNN; ++k) acc[k] = 0.f;
  float base = 0.f;
#pragma unroll 2
  for (int d = 0; d < CH; d += 4) {
    const float4 wa = w3p[(d >> 2) * 64 + c];         // W3[c][d..d+3]
    const float4 wq = w3p[(16 + (d >> 2)) * 64 + c];  // W3[c][64+d..64+d+3]
    float a0 = wa.x, a1 = wa.y, a2 = wa.z, a3 = wa.w;
    float q0 = wq.x, q1 = wq.y, q2 = wq.z, q3 = wq.w;
    const float4 ct = *(const float4*)&xct[d];
    base += ct.x * (q0 - a0) + ct.y * (q1 - a1) + ct.z * (q2 - a2) + ct.w * (q3 - a3);
#pragma unroll
    for (int k = 0; k < KNN; ++k) {
      const float4 nb = *(const float4*)&xin[((size_t)b * N_ + nrow[k]) * CH + d];
      acc[k] += nb.x * a0 + nb.y * a1 + nb.z * a2 + nb.w * a3;
    }
  }
  float h1r[KNN];
#pragma unroll
  for (int k = 0; k < KNN; ++k) h1r[k] = lrelu((acc[k] + base) * sc0 + sh0);

  // wave-local h1 staging; no barrier (wave-synchronous LDS order)
  float* hp = h1s[p];
#pragma unroll
  for (int k = 0; k < KNN; ++k) hp[k * CH + c] = h1r[k];

  float acc2[KNN];
#pragma unroll
  for (int k = 0; k < KNN; ++k) acc2[k] = 0.f;
#pragma unroll 2
  for (int g = 0; g < 16; ++g) {       // cc ascending, identical FMA order to scalar cc loop
    const float4 w = w4p[g * 64 + c];
    if (g & 1) {
#pragma unroll
      for (int k = 0; k < KNN; ++k) {
        float hx = rdlane(h1r[k], g * 4 + 0);
        float hy = rdlane(h1r[k], g * 4 + 1);
        float hz = rdlane(h1r[k], g * 4 + 2);
        float hw = rdlane(h1r[k], g * 4 + 3);
        acc2[k] += hx * w.x; acc2[k] += hy * w.y; acc2[k] += hz * w.z; acc2[k] += hw * w.w;
      }
    } else {
#pragma unroll
      for (int k = 0; k < KNN; ++k) {
        const float4 hv = *(const float4*)&hp[k * CH + g * 4];
        acc2[k] += hv.x * w.x; acc2[k] += hv.y * w.y; acc2[k] += hv.z * w.z; acc2[k] += hv.w * w.w;
      }
    }
  }
  float mx = -INFINITY;
#pragma unroll
  for (int k = 0; k < KNN; ++k) mx = fmaxf(mx, lrelu(acc2[k] * sc1 + sh1));
  xout[((size_t)b * N_ + n0 + p) * CH + c] = mx;
}

// ---------------- stage3: edge(64,K=128 MFMA6) -> 64 -> max_k (x3b does NOT feed KNN) ----------------
__global__ __launch_bounds__(256) void stage3_kernel(
    const float* __restrict__ xf, const int* __restrict__ idx,
    const ushort16* __restrict__ wpAh, const ushort16* __restrict__ wpAm, const ushort16* __restrict__ wpAl,
    const float* __restrict__ g0, const float* __restrict__ b0,
    const float* __restrict__ m0, const float* __restrict__ v0,
    float* __restrict__ xoutf) {
  __shared__ int sidx[160];
  __shared__ u32 h2k[512];
  const int b = blockIdx.y, n0 = blockIdx.x * 8;
  const int tid = threadIdx.x, l = tid & 63, wv = tid >> 6;

  for (int i = tid; i < 160; i += 256) sidx[i] = idx[((size_t)b * N_ + n0 + i / KNN) * KNN + i % KNN];
  for (int i = tid; i < 512; i += 256) h2k[i] = 0u;
  __syncthreads();

  float sc1[4], sh1[4];
#pragma unroll
  for (int nt = 0; nt < 4; ++nt) {
    int ch = nt * 16 + (l & 15);
    double rs = 1.0 / sqrt((double)v0[ch] + 1e-5);
    sc1[nt] = (float)((double)g0[ch] * rs); sh1[nt] = b0[ch] - m0[ch] * sc1[nt];
  }
  const int lg = (l >> 4) << 3;

  for (int mt = wv; mt < 10; mt += 4) {
    const int row = mt * 16 + (l & 15);
    const int nb = sidx[row];
    const int p = row / KNN;
    const float* xnb = xf + ((size_t)b * N_ + nb) * CH;
    const float* xct = xf + ((size_t)b * N_ + n0 + p) * CH;

    f4v acc[4];
#pragma unroll
    for (int nt = 0; nt < 4; ++nt) acc[nt] = (f4v){0.f, 0.f, 0.f, 0.f};
#pragma unroll
    for (int kk = 0; kk < 4; ++kk) {
      const float* src = (kk < 2) ? (xnb + kk * 32 + lg) : (xct + (kk - 2) * 32 + lg);
      s8v a0, a1, a2;
      split3(src, a0, a1, a2);
#pragma unroll
      for (int nt = 0; nt < 4; ++nt) {
        int wo = ((kk * 4 + nt) * 64 + l) << 3;
        s8v bh = *(const s8v*)&wpAh[wo];
        s8v bm = *(const s8v*)&wpAm[wo];
        s8v bl = *(const s8v*)&wpAl[wo];
        MFMA6(acc[nt], a0, a1, a2, bh, bm, bl)
      }
    }
#pragma unroll
    for (int nt = 0; nt < 4; ++nt)
#pragma unroll
      for (int r = 0; r < 4; ++r) {
        float v = lrelu(acc[nt][r] * sc1[nt] + sh1[nt]);
        int row2 = mt * 16 + ((l >> 4) << 2) + r;
        atomicMax(&h2k[(row2 / KNN) * 64 + nt * 16 + (l & 15)], enc_f32(v));
      }
  }
  __syncthreads();
  for (int i = tid; i < 512; i += 256) {
    size_t o = ((size_t)b * N_ + n0 + (i >> 6)) * CH + (i & 63);
    xoutf[o] = dec_f32(h2k[i]);
  }
}

// ---------------- stage6: x4(192) -> 1024 via MFMA6 (no KNN downstream), BN+LReLU, max ----------------
// grid (N/32, B), block 256 = 4 waves; wave wv owns N-tiles [wv*16, wv*16+16); 2 M-tiles (32 points)
__global__ __launch_bounds__(256) void stage6_kernel(
    const float* __restrict__ x1, const float* __restrict__ x2, const float* __restrict__ x3,
    const ushort16* __restrict__ wp6h, const ushort16* __restrict__ wp6m, const ushort16* __restrict__ wp6l,
    const float* __restrict__ g6, const float* __restrict__ b6,
    const float* __restrict__ m6, const float* __restrict__ v6,
    u32* __restrict__ gkeys) {
  const int b = blockIdx.y, n0 = blockIdx.x * 32;
  const int tid = threadIdx.x, l = tid & 63, wv = tid >> 6;
  const int r16 = l & 15, lg = (l >> 4) << 3;

  f4v acc[2][16];
#pragma unroll
  for (int m = 0; m < 2; ++m)
#pragma unroll
    for (int nt = 0; nt < 16; ++nt) acc[m][nt] = (f4v){0.f, 0.f, 0.f, 0.f};

  const float* srcs[3] = {x1, x2, x3};
#pragma unroll
  for (int kk = 0; kk < 6; ++kk) {
    const float* src = srcs[kk >> 1];
    const int col = ((kk & 1) << 5) + lg;
    s8v a0[2], a1[2], a2[2];
#pragma unroll
    for (int m = 0; m < 2; ++m)
      split3(src + ((size_t)b * N_ + n0 + m * 16 + r16) * CH + col, a0[m], a1[m], a2[m]);
#pragma unroll
    for (int nt = 0; nt < 16; ++nt) {
      int t = kk * 64 + wv * 16 + nt;
      int wo = (t * 64 + l) << 3;
      s8v bh = *(const s8v*)&wp6h[wo];
      s8v bm = *(const s8v*)&wp6m[wo];
      s8v bl = *(const s8v*)&wp6l[wo];
      MFMA6(acc[0][nt], a0[0], a1[0], a2[0], bh, bm, bl)
      MFMA6(acc[1][nt], a0[1], a1[1], a2[1], bh, bm, bl)
    }
  }

#pragma unroll
  for (int nt = 0; nt < 16; ++nt) {
    const int ch = (wv * 16 + nt) * 16 + r16;
    double rs = 1.0 / sqrt((double)v6[ch] + 1e-5);
    const float sc = (float)((double)g6[ch] * rs);
    const float sh = b6[ch] - m6[ch] * sc;
    float mx = -INFINITY;
#pragma unroll
    for (int m = 0; m < 2; ++m)
#pragma unroll
      for (int r = 0; r < 4; ++r) mx = fmaxf(mx, lrelu(acc[m][nt][r] * sc + sh));
    mx = fmaxf(mx, __shfl_xor(mx, 16));
    mx = fmaxf(mx, __shfl_xor(mx, 32));
    if (l < 16) atomicMax(&gkeys[(size_t)b * 1024 + (wv * 16 + nt) * 16 + l], enc_f32(mx));
  }
}

__global__ __launch_bounds__(256) void feat_kernel(const u32* __restrict__ gkeys, float* __restrict__ out) {
  int i = blockIdx.x * 256 + threadIdx.x;
  if (i < 8192) out[i] = dec_f32(gkeys[i]);
}

// out1[b][c][n] = x4[b][n][c]; LDS-tiled transpose. grid (N/64, B), block 256.
__global__ __launch_bounds__(256) void xpose_kernel(
    const float* __restrict__ x1, const float* __restrict__ x2, const float* __restrict__ x3,
    float* __restrict__ out) {
  __shared__ float tile[64][65];
  const int b = blockIdx.y;
  const int n0 = blockIdx.x * 64;
  const float* srcs[3] = {x1, x2, x3};
#pragma unroll
  for (int s = 0; s < 3; ++s) {
    const float* src = srcs[s];
    {
      const int row = threadIdx.x >> 2, cb = (threadIdx.x & 3) * 16;
      const float4* rp = (const float4*)&src[((size_t)b * N_ + n0 + row) * CH + cb];
      float4 v0 = rp[0], v1 = rp[1], v2 = rp[2], v3 = rp[3];
      float* tp = &tile[row][cb];
      tp[0] = v0.x; tp[1] = v0.y; tp[2] = v0.z; tp[3] = v0.w;
      tp[4] = v1.x; tp[5] = v1.y; tp[6] = v1.z; tp[7] = v1.w;
      tp[8] = v2.x; tp[9] = v2.y; tp[10] = v2.z; tp[11] = v2.w;
      tp[12] = v3.x; tp[13] = v3.y; tp[14] = v3.z; tp[15] = v3.w;
    }
    __syncthreads();
    {
      const int n = threadIdx.x & 63;
      const int cg = (threadIdx.x >> 6) * 16;
      for (int c = cg; c < cg + 16; ++c)
        out[((size_t)b * 192 + s * 64 + c) * N_ + n0 + n] = tile[n][c];
    }
    __syncthreads();
  }
}

extern "C" void kernel_launch(void* const* d_in, const int* in_sizes, int n_in,
                              void* d_out, int out_size, void* d_ws, size_t ws_size,
                              hipStream_t stream) {
  const float* x   = (const float*)d_in[0];
  const float* W1  = (const float*)d_in[1];
  const float* W2  = (const float*)d_in[2];
  const float* W3  = (const float*)d_in[3];
  const float* W4  = (const float*)d_in[4];
  const float* W5  = (const float*)d_in[5];
  const float* W6  = (const float*)d_in[6];
  const float* bng = (const float*)d_in[7];
  const float* bnb = (const float*)d_in[8];
  const float* bnm = (const float*)d_in[9];
  const float* bnv = (const float*)d_in[10];
  const float* g6  = (const float*)d_in[11];
  const float* b6  = (const float*)d_in[12];
  const float* m6  = (const float*)d_in[13];
  const float* v6  = (const float*)d_in[14];
  float* out = (float*)d_out;

  float* ws = (float*)d_ws;
  float* x1b  = ws;                        // 1048576 f32
  float* x2b  = x1b + 1048576;
  float* x3b  = x2b + 1048576;
  u32*   gkeys = (u32*)(x3b + 1048576);    // 8192
  int*   idxb  = (int*)(gkeys + 8192);     // 327680
  ushort16* wp5h = (ushort16*)(idxb + 327680);   // 8192 ushorts
  ushort16* wp5m = wp5h + 8192;
  ushort16* wp5l = wp5m + 8192;
  ushort16* wp6h = wp5l + 8192;                  // 196608 ushorts each
  ushort16* wp6m = wp6h + 196608;
  ushort16* wp6l = wp6m + 196608;
  float4* w2p = (float4*)(wp6l + 196608);        // 1024 float4
  float4* w3p = w2p + 1024;                      // 2048 float4
  float4* w4p = w3p + 2048;                      // 1024 float4

  prep_kernel<<<768, 256, 0, stream>>>(W2, W3, W4, W5, W6,
                                       w2p, w3p, w4p,
                                       wp5h, wp5m, wp5l,
                                       wp6h, wp6m, wp6l, gkeys);

  knn_kernel<<<dim3(N_ / QPB, B_), 256, 0, stream>>>(x, 3, 0, idxb);
  stage1_kernel<<<dim3(N_ / 4, B_), 256, 0, stream>>>(
      x, idxb, W1, w2p,
      bng + 0, bnb + 0, bnm + 0, bnv + 0,
      bng + 64, bnb + 64, bnm + 64, bnv + 64, x1b);

  knn_kernel<<<dim3(N_ / QPB, B_), 256, 0, stream>>>(x1b, 64, 6, idxb);
  stage2_kernel<<<dim3(N_ / 4, B_), 256, 0, stream>>>(
      x1b, idxb, w3p, w4p,
      bng + 128, bnb + 128, bnm + 128, bnv + 128,
      bng + 192, bnb + 192, bnm + 192, bnv + 192, x2b);

  knn_kernel<<<dim3(N_ / QPB, B_), 256, 0, stream>>>(x2b, 64, 6, idxb);
  stage3_kernel<<<dim3(N_ / 8, B_), 256, 0, stream>>>(
      x2b, idxb, wp5h, wp5m, wp5l,
      bng + 256, bnb + 256, bnm + 256, bnv + 256, x3b);

  stage6_kernel<<<dim3(N_ / 32, B_), 256, 0, stream>>>(
      x1b, x2b, x3b, wp6h, wp6m, wp6l, g6, b6, m6, v6, gkeys);
  feat_kernel<<<32, 256, 0, stream>>>(gkeys, out);
  xpose_kernel<<<dim3(N_ / 64, B_), 256, 0, stream>>>(x1b, x2b, x3b, out + 8192);
}

// Round 11
// 648.321 us; speedup vs baseline: 1.1826x; 1.1826x over previous
//
#include <hip/hip_runtime.h>
#include <hip/hip_bf16.h>
#include <math.h>

#define B_ 8
#define N_ 2048
#define KNN 20
#define CH 64

typedef unsigned int u32;
typedef unsigned short ushort16;
typedef __attribute__((ext_vector_type(8))) short s8v;   // 8 bf16 = 4 VGPR (MFMA A/B frag)
typedef __attribute__((ext_vector_type(4))) float f4v;   // MFMA C/D frag

__device__ __forceinline__ float lrelu(float z) { return z >= 0.0f ? z : 0.2f * z; }

__device__ __forceinline__ u32 enc_f32(float f) {
  u32 u = __float_as_uint(f);
  return (u & 0x80000000u) ? ~u : (u | 0x80000000u);
}
__device__ __forceinline__ float dec_f32(u32 u) {
  u32 bits = (u & 0x80000000u) ? (u ^ 0x80000000u) : ~u;
  return __uint_as_float(bits);
}
__device__ __forceinline__ ushort16 f2bf(float f) {   // RNE bf16
  u32 u = __float_as_uint(f);
  u = (u + 0x7fffu + ((u >> 16) & 1u)) >> 16;
  return (ushort16)u;
}
__device__ __forceinline__ float bf2f(ushort16 h) { return __uint_as_float(((u32)h) << 16); }

// 3-way split of 8 contiguous fp32: v = a0 + a1 + a2 (covers all 24 mantissa bits)
__device__ __forceinline__ void split3(const float* __restrict__ p, s8v& a0, s8v& a1, s8v& a2) {
#pragma unroll
  for (int j = 0; j < 8; ++j) {
    float v = p[j];
    ushort16 h0 = f2bf(v);
    float r = v - bf2f(h0);                 // exact
    u32 ru = __float_as_uint(r);
    a0[j] = (short)h0;
    a1[j] = (short)(ru >> 16);              // truncation
    float r2 = r - __uint_as_float(ru & 0xFFFF0000u);  // exact
    a2[j] = (short)f2bf(r2);
  }
}

// 6-product fp32-grade MFMA: acc += (A0+A1+A2)(B0+B1+B2) minus O(2^-25) terms
#define MFMA6(ACC, A0, A1, A2, B0, B1, B2)                                   \
  ACC = __builtin_amdgcn_mfma_f32_16x16x32_bf16(A0, B0, ACC, 0, 0, 0);       \
  ACC = __builtin_amdgcn_mfma_f32_16x16x32_bf16(A0, B1, ACC, 0, 0, 0);       \
  ACC = __builtin_amdgcn_mfma_f32_16x16x32_bf16(A1, B0, ACC, 0, 0, 0);       \
  ACC = __builtin_amdgcn_mfma_f32_16x16x32_bf16(A0, B2, ACC, 0, 0, 0);       \
  ACC = __builtin_amdgcn_mfma_f32_16x16x32_bf16(A1, B1, ACC, 0, 0, 0);       \
  ACC = __builtin_amdgcn_mfma_f32_16x16x32_bf16(A2, B0, ACC, 0, 0, 0);

__device__ __forceinline__ void wsplit(float v, ushort16& h0, ushort16& h1, ushort16& h2) {
  h0 = f2bf(v);
  float r = v - bf2f(h0);
  h1 = f2bf(r);
  float r2 = r - bf2f(h1);
  h2 = f2bf(r2);
}

// ---------------- prep: float4 weight quads (bit-exact copies) + MFMA6 packs + gkeys ----------------
// B-frag lane map (16x16x32): col = l&15, k = (l>>4)*8 + j.
__global__ __launch_bounds__(256) void prep_kernel(
    const float* __restrict__ W2, const float* __restrict__ W3, const float* __restrict__ W4,
    const float* __restrict__ W5, const float* __restrict__ W6,
    float4* __restrict__ w2p, float4* __restrict__ w3p, float4* __restrict__ w4p,
    ushort16* __restrict__ wp5h, ushort16* __restrict__ wp5m, ushort16* __restrict__ wp5l,
    ushort16* __restrict__ wp6h, ushort16* __restrict__ wp6m, ushort16* __restrict__ wp6l,
    u32* __restrict__ gkeys) {
  int i = blockIdx.x * 256 + threadIdx.x;
  if (i < 196608) {              // wp6 pack: t = kk*64+nt (kk<6), d = kk*32+(l>>4)*8+j, ch = nt*16+(l&15)
    int j = i & 7, l = (i >> 3) & 63, t = i >> 9;
    int kk = t >> 6, nt = t & 63;
    int d = kk * 32 + ((l >> 4) << 3) + j;
    int ch = nt * 16 + (l & 15);
    ushort16 a, b, c;
    wsplit(W6[ch * 192 + d], a, b, c);
    wp6h[i] = a; wp6m[i] = b; wp6l[i] = c;
  }
  if (i < 8192) {
    gkeys[i] = 0u;
    // MFMA6 pack for W5 (Wcat: d<64 -> WA; d>=64 -> WB-WA)
    int j = i & 7, l = (i >> 3) & 63, tile = i >> 9;
    int kk = tile >> 2, nt = tile & 3;
    int d = kk * 32 + ((l >> 4) << 3) + j;
    int ch = nt * 16 + (l & 15);
    float v5 = (d < 64) ? W5[ch * 128 + d] : (W5[ch * 128 + d] - W5[ch * 128 + d - 64]);
    ushort16 a, b, c;
    wsplit(v5, a, b, c); wp5h[i] = a; wp5m[i] = b; wp5l[i] = c;
  }
  if (i < 2048) {                // w3p[g*64+c] = W3[c][4g..4g+3], g<32 (a-quads g<16, q-quads g>=16)
    int g = i >> 6, c_ = i & 63;
    w3p[i] = *(const float4*)&W3[c_ * 128 + 4 * g];
  }
  if (i < 1024) {                // w2p/w4p[g*64+c] = W[c][4g..4g+3]
    int g = i >> 6, c_ = i & 63;
    w2p[i] = *(const float4*)&W2[c_ * 64 + 4 * g];
    w4p[i] = *(const float4*)&W4[c_ * 64 + 4 * g];
  }
}

// ---------------- KNN: fp32 filter + fp64 rerank; parallel 8-lane tournament merge ----------------
#define QPB 32
#define SL 8
#define CSL (N_ / SL)
#define CAP 31

__global__ __launch_bounds__(256) void knn_kernel(const float* __restrict__ p, int ld, int off,
                                                  int* __restrict__ idxout) {
  __shared__ __align__(16) char arena[64640];
  float4* pts = (float4*)arena;
  int* buf = (int*)(arena + 32896);
  double* dls = (double*)arena;
  int* ils = (int*)(arena + 40960);

  const int b = blockIdx.y;
  const float* pb = p + (size_t)b * N_ * ld + off;
  for (int j = threadIdx.x; j < N_; j += 256) {
    pts[j + (j >> 8)] = make_float4(pb[(size_t)j * ld + 0], pb[(size_t)j * ld + 1],
                                    pb[(size_t)j * ld + 2], 0.f);
  }
  __syncthreads();

  const int t = threadIdx.x & 7;
  const int qloc = threadIdx.x >> 3;
  const int q = blockIdx.x * QPB + qloc;
  const float4 qp = pts[q + (q >> 8)];
  const int jb = t * CSL;
  const float4* myp = pts + jb + t;

  float d0 = 1e30f, d1 = 1e30f, d2 = 1e30f;
#pragma unroll 4
  for (int i = 0; i < CSL; ++i) {
    float4 c = myp[i];
    float dx = qp.x - c.x, dy = qp.y - c.y, dz = qp.z - c.z;
    float d = fmaf(dz, dz, fmaf(dy, dy, dx * dx));
    float lo = fminf(d, d0); float hi = fmaxf(d, d0); d0 = lo;
    float m1 = fminf(d1, hi); float c1 = fmaxf(d1, hi); d1 = m1;
    d2 = fminf(d2, c1);
  }
  float thr = d2;
#pragma unroll
  for (int s = 1; s < 8; s <<= 1) thr = fmaxf(thr, __shfl_xor(thr, s));
  thr = thr * 1.0001f + 1e-7f;

  int cnt = 0;
  int* mybuf = buf + threadIdx.x * CAP;
#pragma unroll 4
  for (int i = 0; i < CSL; ++i) {
    float4 c = myp[i];
    float dx = qp.x - c.x, dy = qp.y - c.y, dz = qp.z - c.z;
    float d = fmaf(dz, dz, fmaf(dy, dy, dx * dx));
    if (d <= thr) {
      if (cnt < CAP) mybuf[cnt] = jb + i;
      ++cnt;
    }
  }

  double ld_[KNN]; int li_[KNN];
#pragma unroll
  for (int u = 0; u < KNN; ++u) { ld_[u] = 1e300; li_[u] = 0x7fffffff; }

  const bool ovf = cnt > CAP;
  const int m = ovf ? 0 : cnt;
  for (int e = 0; e < m; ++e) {
    int j = mybuf[e];
    float4 c = pts[j + (j >> 8)];
    double dx = (double)qp.x - (double)c.x;
    double dy = (double)qp.y - (double)c.y;
    double dz = (double)qp.z - (double)c.z;
    double d = dx * dx + dy * dy + dz * dz;
    if (d < ld_[KNN - 1]) {
      ld_[KNN - 1] = d; li_[KNN - 1] = j;
#pragma unroll
      for (int u = KNN - 1; u > 0; --u) {
        if (ld_[u] < ld_[u - 1]) {
          double td = ld_[u]; ld_[u] = ld_[u - 1]; ld_[u - 1] = td;
          int ti = li_[u]; li_[u] = li_[u - 1]; li_[u - 1] = ti;
        }
      }
    }
  }
  if (ovf) {
    for (int i = 0; i < CSL; ++i) {
      int j = jb + i;
      float4 c = myp[i];
      double dx = (double)qp.x - (double)c.x;
      double dy = (double)qp.y - (double)c.y;
      double dz = (double)qp.z - (double)c.z;
      double d = dx * dx + dy * dy + dz * dz;
      if (d < ld_[KNN - 1]) {
        ld_[KNN - 1] = d; li_[KNN - 1] = j;
#pragma unroll
        for (int u = KNN - 1; u > 0; --u) {
          if (ld_[u] < ld_[u - 1]) {
            double td = ld_[u]; ld_[u] = ld_[u - 1]; ld_[u - 1] = td;
            int ti = li_[u]; li_[u] = li_[u - 1]; li_[u - 1] = ti;
          }
        }
      }
    }
  }
  __syncthreads();
#pragma unroll
  for (int u = 0; u < KNN; ++u) {
    dls[threadIdx.x * KNN + u] = ld_[u];
    ils[threadIdx.x * KNN + u] = li_[u];
  }
  __syncthreads();

  // ---- parallel 8-lane tournament merge, lexicographic (d, idx) — same selection
  //      order as the serial CONSIDER chain (strict (d,idx) min; butterfly is
  //      order-independent for a strict total order) ----
  {
    int h = 0;                                   // head into my own sorted list
    int* outp = idxout + ((size_t)b * N_ + q) * KNN;
    const int mybase = threadIdx.x * KNN;
    for (int r = 0; r < KNN; ++r) {
      double dv = dls[mybase + h];
      int iv = ils[mybase + h];
      int sv = t;
#pragma unroll
      for (int s = 1; s < 8; s <<= 1) {          // lanes of a query are consecutive; xor<8 stays in-group
        double od = __shfl_xor(dv, s);
        int oi = __shfl_xor(iv, s);
        int os = __shfl_xor(sv, s);
        bool take = (od < dv) || (od == dv && oi < iv);
        dv = take ? od : dv;
        iv = take ? oi : iv;
        sv = take ? os : sv;
      }
      if (t == 0) outp[r] = iv;
      if (sv == t) ++h;                          // winner advances (h <= r+1 <= 20, reads always h<=19)
    }
  }
}

// ---------------- stage1: bit-exact fp32 (x1b feeds KNN); GEMM2 via LDS broadcast (R9) ----------------
__global__ __launch_bounds__(256) void stage1_kernel(
    const float* __restrict__ x, const int* __restrict__ idx,
    const float* __restrict__ W1, const float4* __restrict__ w2p,
    const float* __restrict__ g0, const float* __restrict__ b0,
    const float* __restrict__ m0, const float* __restrict__ v0,
    const float* __restrict__ g1, const float* __restrict__ b1,
    const float* __restrict__ m1, const float* __restrict__ v1,
    float* __restrict__ x1out) {
  __shared__ float nbs[4][KNN][3];
  __shared__ float ctrs[4][3];
  __shared__ int sidx[4][KNN];
  __shared__ float h1s[4][KNN * CH];   // 20KB wave-local h1 staging
  const int b = blockIdx.y;
  const int n0 = blockIdx.x * 4;
  const int p = threadIdx.x >> 6, c = threadIdx.x & 63;

  for (int i = threadIdx.x; i < 4 * KNN; i += 256)
    sidx[i / KNN][i % KNN] = idx[((size_t)b * N_ + n0 + i / KNN) * KNN + i % KNN];
  __syncthreads();
  for (int i = threadIdx.x; i < 4 * KNN * 3; i += 256) {
    int pp = i / (KNN * 3), r = i % (KNN * 3), k = r / 3, d = r % 3;
    nbs[pp][k][d] = x[((size_t)b * N_ + sidx[pp][k]) * 3 + d];
  }
  if (threadIdx.x < 12) {
    int pp = threadIdx.x / 3, d = threadIdx.x % 3;
    ctrs[pp][d] = x[((size_t)b * N_ + n0 + pp) * 3 + d];
  }
  __syncthreads();

  float sc0, sh0, sc1, sh1;
  {
    double rs = 1.0 / sqrt((double)v0[c] + 1e-5);
    sc0 = (float)((double)g0[c] * rs); sh0 = b0[c] - m0[c] * sc0;
    rs = 1.0 / sqrt((double)v1[c] + 1e-5);
    sc1 = (float)((double)g1[c] * rs); sh1 = b1[c] - m1[c] * sc1;
  }

  const float cx = ctrs[p][0], cy = ctrs[p][1], cz = ctrs[p][2];
  const float wa0 = W1[c * 6 + 0], wa1 = W1[c * 6 + 1], wa2 = W1[c * 6 + 2];
  const float wb0 = W1[c * 6 + 3], wb1 = W1[c * 6 + 4], wb2 = W1[c * 6 + 5];
  const float cbase = cx * wb0 + cy * wb1 + cz * wb2;

  float h1r[KNN];
#pragma unroll
  for (int k = 0; k < KNN; ++k) {
    float a = (nbs[p][k][0] - cx) * wa0 + (nbs[p][k][1] - cy) * wa1 + (nbs[p][k][2] - cz) * wa2 + cbase;
    h1r[k] = lrelu(a * sc0 + sh0);
  }

  // stage h1 in wave-local LDS (same bits), GEMM2 reads are wave-uniform broadcasts
  float* hp = h1s[p];
#pragma unroll
  for (int k = 0; k < KNN; ++k) hp[k * CH + c] = h1r[k];

  float acc2[KNN];
#pragma unroll
  for (int k = 0; k < KNN; ++k) acc2[k] = 0.f;
  for (int g = 0; g < 16; ++g) {       // cc = 4g..4g+3, ascending (same FMA order as scalar cc loop)
    const float4 w = w2p[g * 64 + c];
#pragma unroll
    for (int k = 0; k < KNN; ++k) {
      const float4 hv = *(const float4*)&hp[k * CH + g * 4];
      acc2[k] += hv.x * w.x; acc2[k] += hv.y * w.y; acc2[k] += hv.z * w.z; acc2[k] += hv.w * w.w;
    }
  }
  float mx = -INFINITY;
#pragma unroll
  for (int k = 0; k < KNN; ++k) mx = fmaxf(mx, lrelu(acc2[k] * sc1 + sh1));
  x1out[((size_t)b * N_ + n0 + p) * CH + c] = mx;
}

// ---------------- stage2: bit-exact fp32 (x2b feeds KNN); vec weights + LDS-broadcast GEMM2 (R9) ----------------
__global__ __launch_bounds__(256) void stage2_kernel(
    const float* __restrict__ xin, const int* __restrict__ idx,
    const float4* __restrict__ w3p, const float4* __restrict__ w4p,
    const float* __restrict__ g0, const float* __restrict__ b0,
    const float* __restrict__ m0, const float* __restrict__ v0,
    const float* __restrict__ g1, const float* __restrict__ b1,
    const float* __restrict__ m1, const float* __restrict__ v1,
    float* __restrict__ xout) {
  __shared__ float nbs[4][KNN][CH];   // 20KB; reused as per-wave h1 staging after GEMM1
  __shared__ float ctrs[4][CH];
  __shared__ int sidx[4][KNN];
  const int b = blockIdx.y, n0 = blockIdx.x * 4;
  const int p = threadIdx.x >> 6, c = threadIdx.x & 63;

  for (int i = threadIdx.x; i < 4 * KNN; i += 256)
    sidx[i / KNN][i % KNN] = idx[((size_t)b * N_ + n0 + i / KNN) * KNN + i % KNN];
  __syncthreads();
  for (int i = threadIdx.x; i < 4 * KNN * 16; i += 256) {
    int pp = i / (KNN * 16), r = i % (KNN * 16), k = r >> 4, d4 = (r & 15) * 4;
    const float4 v = *(const float4*)&xin[((size_t)b * N_ + sidx[pp][k]) * CH + d4];
    *(float4*)&nbs[pp][k][d4] = v;
  }
  for (int i = threadIdx.x; i < 4 * 16; i += 256) {
    int pp = i / 16, d4 = (i % 16) * 4;
    *(float4*)&ctrs[pp][d4] = *(const float4*)&xin[((size_t)b * N_ + n0 + pp) * CH + d4];
  }
  __syncthreads();

  float sc0, sh0, sc1, sh1;
  {
    double rs = 1.0 / sqrt((double)v0[c] + 1e-5);
    sc0 = (float)((double)g0[c] * rs); sh0 = b0[c] - m0[c] * sc0;
    rs = 1.0 / sqrt((double)v1[c] + 1e-5);
    sc1 = (float)((double)g1[c] * rs); sh1 = b1[c] - m1[c] * sc1;
  }

  float acc[KNN];
#pragma unroll
  for (int k = 0; k < KNN; ++k) acc[k] = 0.f;
  float base = 0.f;
#pragma unroll 4
  for (int d = 0; d < CH; d += 4) {
    const float4 wa = w3p[(d >> 2) * 64 + c];         // W3[c][d..d+3]
    const float4 wq = w3p[(16 + (d >> 2)) * 64 + c];  // W3[c][64+d..64+d+3]
    float a0 = wa.x, a1 = wa.y, a2 = wa.z, a3 = wa.w;
    float q0 = wq.x, q1 = wq.y, q2 = wq.z, q3 = wq.w;
    const float4 ct = *(const float4*)&ctrs[p][d];
    base += ct.x * (q0 - a0) + ct.y * (q1 - a1) + ct.z * (q2 - a2) + ct.w * (q3 - a3);
#pragma unroll
    for (int k = 0; k < KNN; ++k) {
      const float4 nb = *(const float4*)&nbs[p][k][d];
      acc[k] += nb.x * a0 + nb.y * a1 + nb.z * a2 + nb.w * a3;
    }
  }
  float h1r[KNN];
#pragma unroll
  for (int k = 0; k < KNN; ++k) h1r[k] = lrelu((acc[k] + base) * sc0 + sh0);

  // wave-local h1 staging in our own (now-dead) nbs slice; no barrier (wave-synchronous LDS order)
  float* hp = &nbs[p][0][0];
#pragma unroll
  for (int k = 0; k < KNN; ++k) hp[k * CH + c] = h1r[k];

  float acc2[KNN];
#pragma unroll
  for (int k = 0; k < KNN; ++k) acc2[k] = 0.f;
  for (int g = 0; g < 16; ++g) {       // cc ascending, identical FMA order to scalar cc loop
    const float4 w = w4p[g * 64 + c];
#pragma unroll
    for (int k = 0; k < KNN; ++k) {
      const float4 hv = *(const float4*)&hp[k * CH + g * 4];
      acc2[k] += hv.x * w.x; acc2[k] += hv.y * w.y; acc2[k] += hv.z * w.z; acc2[k] += hv.w * w.w;
    }
  }
  float mx = -INFINITY;
#pragma unroll
  for (int k = 0; k < KNN; ++k) mx = fmaxf(mx, lrelu(acc2[k] * sc1 + sh1));
  xout[((size_t)b * N_ + n0 + p) * CH + c] = mx;
}

// ---------------- stage3: edge(64,K=128 MFMA6) -> 64 -> max_k (x3b does NOT feed KNN) ----------------
__global__ __launch_bounds__(256) void stage3_kernel(
    const float* __restrict__ xf, const int* __restrict__ idx,
    const ushort16* __restrict__ wpAh, const ushort16* __restrict__ wpAm, const ushort16* __restrict__ wpAl,
    const float* __restrict__ g0, const float* __restrict__ b0,
    const float* __restrict__ m0, const float* __restrict__ v0,
    float* __restrict__ xoutf) {
  __shared__ int sidx[160];
  __shared__ u32 h2k[512];
  const int b = blockIdx.y, n0 = blockIdx.x * 8;
  const int tid = threadIdx.x, l = tid & 63, wv = tid >> 6;

  for (int i = tid; i < 160; i += 256) sidx[i] = idx[((size_t)b * N_ + n0 + i / KNN) * KNN + i % KNN];
  for (int i = tid; i < 512; i += 256) h2k[i] = 0u;
  __syncthreads();

  float sc1[4], sh1[4];
#pragma unroll
  for (int nt = 0; nt < 4; ++nt) {
    int ch = nt * 16 + (l & 15);
    double rs = 1.0 / sqrt((double)v0[ch] + 1e-5);
    sc1[nt] = (float)((double)g0[ch] * rs); sh1[nt] = b0[ch] - m0[ch] * sc1[nt];
  }
  const int lg = (l >> 4) << 3;

  for (int mt = wv; mt < 10; mt += 4) {
    const int row = mt * 16 + (l & 15);
    const int nb = sidx[row];
    const int p = row / KNN;
    const float* xnb = xf + ((size_t)b * N_ + nb) * CH;
    const float* xct = xf + ((size_t)b * N_ + n0 + p) * CH;

    f4v acc[4];
#pragma unroll
    for (int nt = 0; nt < 4; ++nt) acc[nt] = (f4v){0.f, 0.f, 0.f, 0.f};
#pragma unroll
    for (int kk = 0; kk < 4; ++kk) {
      const float* src = (kk < 2) ? (xnb + kk * 32 + lg) : (xct + (kk - 2) * 32 + lg);
      s8v a0, a1, a2;
      split3(src, a0, a1, a2);
#pragma unroll
      for (int nt = 0; nt < 4; ++nt) {
        int wo = ((kk * 4 + nt) * 64 + l) << 3;
        s8v bh = *(const s8v*)&wpAh[wo];
        s8v bm = *(const s8v*)&wpAm[wo];
        s8v bl = *(const s8v*)&wpAl[wo];
        MFMA6(acc[nt], a0, a1, a2, bh, bm, bl)
      }
    }
#pragma unroll
    for (int nt = 0; nt < 4; ++nt)
#pragma unroll
      for (int r = 0; r < 4; ++r) {
        float v = lrelu(acc[nt][r] * sc1[nt] + sh1[nt]);
        int row2 = mt * 16 + ((l >> 4) << 2) + r;
        atomicMax(&h2k[(row2 / KNN) * 64 + nt * 16 + (l & 15)], enc_f32(v));
      }
  }
  __syncthreads();
  for (int i = tid; i < 512; i += 256) {
    size_t o = ((size_t)b * N_ + n0 + (i >> 6)) * CH + (i & 63);
    xoutf[o] = dec_f32(h2k[i]);
  }
}

// ---------------- stage6: x4(192) -> 1024 via MFMA6 (no KNN downstream), BN+LReLU, max ----------------
// grid (N/32, B), block 256 = 4 waves; wave wv owns N-tiles [wv*16, wv*16+16); 2 M-tiles (32 points)
__global__ __launch_bounds__(256) void stage6_kernel(
    const float* __restrict__ x1, const float* __restrict__ x2, const float* __restrict__ x3,
    const ushort16* __restrict__ wp6h, const ushort16* __restrict__ wp6m, const ushort16* __restrict__ wp6l,
    const float* __restrict__ g6, const float* __restrict__ b6,
    const float* __restrict__ m6, const float* __restrict__ v6,
    u32* __restrict__ gkeys) {
  const int b = blockIdx.y, n0 = blockIdx.x * 32;
  const int tid = threadIdx.x, l = tid & 63, wv = tid >> 6;
  const int r16 = l & 15, lg = (l >> 4) << 3;

  f4v acc[2][16];
#pragma unroll
  for (int m = 0; m < 2; ++m)
#pragma unroll
    for (int nt = 0; nt < 16; ++nt) acc[m][nt] = (f4v){0.f, 0.f, 0.f, 0.f};

  const float* srcs[3] = {x1, x2, x3};
#pragma unroll
  for (int kk = 0; kk < 6; ++kk) {
    const float* src = srcs[kk >> 1];
    const int col = ((kk & 1) << 5) + lg;
    s8v a0[2], a1[2], a2[2];
#pragma unroll
    for (int m = 0; m < 2; ++m)
      split3(src + ((size_t)b * N_ + n0 + m * 16 + r16) * CH + col, a0[m], a1[m], a2[m]);
#pragma unroll
    for (int nt = 0; nt < 16; ++nt) {
      int t = kk * 64 + wv * 16 + nt;
      int wo = (t * 64 + l) << 3;
      s8v bh = *(const s8v*)&wp6h[wo];
      s8v bm = *(const s8v*)&wp6m[wo];
      s8v bl = *(const s8v*)&wp6l[wo];
      MFMA6(acc[0][nt], a0[0], a1[0], a2[0], bh, bm, bl)
      MFMA6(acc[1][nt], a0[1], a1[1], a2[1], bh, bm, bl)
    }
  }

#pragma unroll
  for (int nt = 0; nt < 16; ++nt) {
    const int ch = (wv * 16 + nt) * 16 + r16;
    double rs = 1.0 / sqrt((double)v6[ch] + 1e-5);
    const float sc = (float)((double)g6[ch] * rs);
    const float sh = b6[ch] - m6[ch] * sc;
    float mx = -INFINITY;
#pragma unroll
    for (int m = 0; m < 2; ++m)
#pragma unroll
      for (int r = 0; r < 4; ++r) mx = fmaxf(mx, lrelu(acc[m][nt][r] * sc + sh));
    mx = fmaxf(mx, __shfl_xor(mx, 16));
    mx = fmaxf(mx, __shfl_xor(mx, 32));
    if (l < 16) atomicMax(&gkeys[(size_t)b * 1024 + (wv * 16 + nt) * 16 + l], enc_f32(mx));
  }
}

__global__ __launch_bounds__(256) void feat_kernel(const u32* __restrict__ gkeys, float* __restrict__ out) {
  int i = blockIdx.x * 256 + threadIdx.x;
  if (i < 8192) out[i] = dec_f32(gkeys[i]);
}

// out1[b][c][n] = x4[b][n][c]; LDS-tiled transpose. grid (N/64, B), block 256.
__global__ __launch_bounds__(256) void xpose_kernel(
    const float* __restrict__ x1, const float* __restrict__ x2, const float* __restrict__ x3,
    float* __restrict__ out) {
  __shared__ float tile[64][65];
  const int b = blockIdx.y;
  const int n0 = blockIdx.x * 64;
  const float* srcs[3] = {x1, x2, x3};
#pragma unroll
  for (int s = 0; s < 3; ++s) {
    const float* src = srcs[s];
    {
      const int row = threadIdx.x >> 2, cb = (threadIdx.x & 3) * 16;
      const float4* rp = (const float4*)&src[((size_t)b * N_ + n0 + row) * CH + cb];
      float4 v0 = rp[0], v1 = rp[1], v2 = rp[2], v3 = rp[3];
      float* tp = &tile[row][cb];
      tp[0] = v0.x; tp[1] = v0.y; tp[2] = v0.z; tp[3] = v0.w;
      tp[4] = v1.x; tp[5] = v1.y; tp[6] = v1.z; tp[7] = v1.w;
      tp[8] = v2.x; tp[9] = v2.y; tp[10] = v2.z; tp[11] = v2.w;
      tp[12] = v3.x; tp[13] = v3.y; tp[14] = v3.z; tp[15] = v3.w;
    }
    __syncthreads();
    {
      const int n = threadIdx.x & 63;
      const int cg = (threadIdx.x >> 6) * 16;
      for (int c = cg; c < cg + 16; ++c)
        out[((size_t)b * 192 + s * 64 + c) * N_ + n0 + n] = tile[n][c];
    }
    __syncthreads();
  }
}

extern "C" void kernel_launch(void* const* d_in, const int* in_sizes, int n_in,
                              void* d_out, int out_size, void* d_ws, size_t ws_size,
                              hipStream_t stream) {
  const float* x   = (const float*)d_in[0];
  const float* W1  = (const float*)d_in[1];
  const float* W2  = (const float*)d_in[2];
  const float* W3  = (const float*)d_in[3];
  const float* W4  = (const float*)d_in[4];
  const float* W5  = (const float*)d_in[5];
  const float* W6  = (const float*)d_in[6];
  const float* bng = (const float*)d_in[7];
  const float* bnb = (const float*)d_in[8];
  const float* bnm = (const float*)d_in[9];
  const float* bnv = (const float*)d_in[10];
  const float* g6  = (const float*)d_in[11];
  const float* b6  = (const float*)d_in[12];
  const float* m6  = (const float*)d_in[13];
  const float* v6  = (const float*)d_in[14];
  float* out = (float*)d_out;

  float* ws = (float*)d_ws;
  float* x1b  = ws;                        // 1048576 f32
  float* x2b  = x1b + 1048576;
  float* x3b  = x2b + 1048576;
  u32*   gkeys = (u32*)(x3b + 1048576);    // 8192
  int*   idxb  = (int*)(gkeys + 8192);     // 327680
  ushort16* wp5h = (ushort16*)(idxb + 327680);   // 8192 ushorts
  ushort16* wp5m = wp5h + 8192;
  ushort16* wp5l = wp5m + 8192;
  ushort16* wp6h = wp5l + 8192;                  // 196608 ushorts each
  ushort16* wp6m = wp6h + 196608;
  ushort16* wp6l = wp6m + 196608;
  float4* w2p = (float4*)(wp6l + 196608);        // 1024 float4
  float4* w3p = w2p + 1024;                      // 2048 float4
  float4* w4p = w3p + 2048;                      // 1024 float4

  prep_kernel<<<768, 256, 0, stream>>>(W2, W3, W4, W5, W6,
                                       w2p, w3p, w4p,
                                       wp5h, wp5m, wp5l,
                                       wp6h, wp6m, wp6l, gkeys);

  knn_kernel<<<dim3(N_ / QPB, B_), 256, 0, stream>>>(x, 3, 0, idxb);
  stage1_kernel<<<dim3(N_ / 4, B_), 256, 0, stream>>>(
      x, idxb, W1, w2p,
      bng + 0, bnb + 0, bnm + 0, bnv + 0,
      bng + 64, bnb + 64, bnm + 64, bnv + 64, x1b);

  knn_kernel<<<dim3(N_ / QPB, B_), 256, 0, stream>>>(x1b, 64, 6, idxb);
  stage2_kernel<<<dim3(N_ / 4, B_), 256, 0, stream>>>(
      x1b, idxb, w3p, w4p,
      bng + 128, bnb + 128, bnm + 128, bnv + 128,
      bng + 192, bnb + 192, bnm + 192, bnv + 192, x2b);

  knn_kernel<<<dim3(N_ / QPB, B_), 256, 0, stream>>>(x2b, 64, 6, idxb);
  stage3_kernel<<<dim3(N_ / 8, B_), 256, 0, stream>>>(
      x2b, idxb, wp5h, wp5m, wp5l,
      bng + 256, bnb + 256, bnm + 256, bnv + 256, x3b);

  stage6_kernel<<<dim3(N_ / 32, B_), 256, 0, stream>>>(
      x1b, x2b, x3b, wp6h, wp6m, wp6l, g6, b6, m6, v6, gkeys);
  feat_kernel<<<32, 256, 0, stream>>>(gkeys, out);
  xpose_kernel<<<dim3(N_ / 64, B_), 256, 0, stream>>>(x1b, x2b, x3b, out + 8192);
}